// Round 1
// 114.378 us; speedup vs baseline: 1.0397x; 1.0397x over previous
//
#include <hip/hip_runtime.h>
#include <hip/hip_fp16.h>

// HartleyConv2d: out[b,o,u,v] = (0.5/132^2) * sum_c [ X*(W+Wf) + Xf*(W-Wf) ]
// X = DHT2(pad1(x) zero-padded to 132); DHT table T[r][k] = cas(2pi r (k+1)/132).
// ALL I/O fp32: x [8,64,128,128], w [64,64,3,3], out [8,64,128,128].
// R9: u-pairing in combine (block uidx produces rows uidx and 131-uidx from ONE
//     P/M staging -> X read once, 528 blocks), bf hoisted (3 MFMA per ds_read),
//     dht2 epilogue vectorized via LDS restage (X padded to 136 cols, linear
//     b128 stores), builders merged into one launch, hgT only for u<=65.

#define SCALE (0.5f / 17424.0f)
#define MFMA  __builtin_amdgcn_mfma_f32_16x16x32_f16

typedef __attribute__((ext_vector_type(8))) _Float16 f16x8;
typedef __attribute__((ext_vector_type(4))) _Float16 f16x4;
typedef __attribute__((ext_vector_type(4))) float    f32x4;

static __device__ __forceinline__ f16x8 scl(f16x8 a, _Float16 s) {
    #pragma unroll
    for (int e = 0; e < 8; ++e) a[e] *= s;
    return a;
}

// ------------------------------------------------------------ build_all ----
// bid 0..143   : Tf rows (144x128 f16, rows >=132 zero)
// bid 144      : cfT [128][8] f16 {1,bv1,bv2,1,bp1,bp2,0,0}
// bid 145..408 : hgT[u][kt][o][c], u = (bid-145)>>2 in 0..65, 4 it-chunks each
__global__ __launch_bounds__(256) void build_all(
    const float* __restrict__ w, _Float16* __restrict__ Tf,
    _Float16* __restrict__ cfT, _Float16* __restrict__ hgT)
{
    const int bid = blockIdx.x;
    const int tid = threadIdx.x;
    const float step = 6.28318530717958647692f / 132.0f;
    if (bid < 144) {
        if (tid < 128) {
            float val = 0.f;
            if (bid < 132) {
                const int m = (bid * (tid + 1)) % 132;
                float s, c;
                sincosf((float)m * step, &s, &c);
                val = c + s;
            }
            Tf[bid * 128 + tid] = (_Float16)val;
        }
        return;
    }
    if (bid == 144) {
        if (tid < 128) {
            const int v = tid;
            float s, c;
            _Float16 o[8];
            o[0] = (_Float16)1.0f; o[3] = (_Float16)1.0f;
            o[6] = (_Float16)0.0f; o[7] = (_Float16)0.0f;
            sincosf((float)((v * 1) % 132) * step, &s, &c);       o[1] = (_Float16)(c + s);
            sincosf((float)((v * 2) % 132) * step, &s, &c);       o[2] = (_Float16)(c + s);
            sincosf((float)(((v + 1) * 1) % 132) * step, &s, &c); o[4] = (_Float16)(c - s);
            sincosf((float)(((v + 1) * 2) % 132) * step, &s, &c); o[5] = (_Float16)(c - s);
            *(f16x8*)(cfT + v * 8) = *(f16x8*)o;
        }
        return;
    }
    const int bid2 = bid - 145;            // 0..263
    const int u = bid2 >> 2;               // 0..65 (only these are used)
    const int itbase = (bid2 & 3) * 4;     // 0,4,8,12
    float a[3], ap[3];
    a[0] = 1.f; ap[0] = 1.f;
    #pragma unroll
    for (int i = 1; i < 3; ++i) {
        float s, c;
        sincosf((float)((u * i) % 132) * step, &s, &c);
        a[i] = c + s;                                   // cas(2pi*u*i/132)
        sincosf((float)(((u + 1) * i) % 132) * step, &s, &c);
        ap[i] = c - s;                                  // cas(-2pi*(u+1)*i/132)
    }
    for (int it = itbase; it < itbase + 4; ++it) {
        const int oc = it * 256 + tid;                  // o*64+c
        const float* wp = w + (size_t)oc * 9;
        float w9[9];
        #pragma unroll
        for (int q = 0; q < 9; ++q) w9[q] = wp[q];
        #pragma unroll
        for (int j = 0; j < 3; ++j) {
            const float h = a[0]*w9[j] + a[1]*w9[3+j] + a[2]*w9[6+j];
            const float g = ap[0]*w9[j] + ap[1]*w9[3+j] + ap[2]*w9[6+j];
            hgT[((size_t)u * 6 + j)     * 4096 + oc] = (_Float16)h;
            hgT[((size_t)u * 6 + 3 + j) * 4096 + oc] = (_Float16)g;
        }
    }
}

// ------------------------------------------------------------ dht2_fused ----
// grid(512): block = one (b,c) plane, 256 thr (4 waves). Tf staged in LDS.
// pass A: Y1l[v][i] = sum_j Tfl[v][j] * x[i][j]
// pass B: X[u][v]   = sum_i Tfl[u][i] * Y1l[v][i]
// epilogue: acc -> Tfl (reuse) -> linear b128 copy-out. X rows padded to 136.
__global__ __launch_bounds__(256, 2) void dht2_fused(
    const float* __restrict__ x, const _Float16* __restrict__ Tf,
    _Float16* __restrict__ X)
{
    const int bc = blockIdx.x;
    const int tid = threadIdx.x, wv = tid >> 6, lane = tid & 63;
    const int col = lane & 15, quad = lane >> 4;
    __shared__ _Float16 Tfl[144][136];   // stride 136 (272 B): conflict-minimal
    __shared__ _Float16 Y1l[144][136];

    const float* xp = x + (size_t)bc * 16384;

    // ---- hoist ALL x loads for this wave's two i-tiles (issued up front)
    float4 xv[2][4][2];
    #pragma unroll
    for (int nt = 0; nt < 2; ++nt) {
        const int ic = (wv * 2 + nt) * 16 + col;
        #pragma unroll
        for (int kc = 0; kc < 4; ++kc) {
            const int k0 = kc * 32 + quad * 8;
            xv[nt][kc][0] = *(const float4*)(xp + ic * 128 + k0);
            xv[nt][kc][1] = *(const float4*)(xp + ic * 128 + k0 + 4);
        }
    }
    // ---- stage Tf -> Tfl (36,864 B in 16B chunks)
    #pragma unroll
    for (int s = 0; s < 9; ++s) {
        const int idx = tid + 256 * s;        // chunk id 0..2303
        const int row = idx >> 4;
        const int ce  = (idx & 15) * 8;
        *(f16x8*)&Tfl[row][ce] = *(const f16x8*)(Tf + (size_t)idx * 8);
    }
    // ---- convert x to f16 B-fragments
    f16x8 bfA[2][4];
    #pragma unroll
    for (int nt = 0; nt < 2; ++nt)
        #pragma unroll
        for (int kc = 0; kc < 4; ++kc) {
            f16x8 t;
            t[0] = (_Float16)xv[nt][kc][0].x; t[1] = (_Float16)xv[nt][kc][0].y;
            t[2] = (_Float16)xv[nt][kc][0].z; t[3] = (_Float16)xv[nt][kc][0].w;
            t[4] = (_Float16)xv[nt][kc][1].x; t[5] = (_Float16)xv[nt][kc][1].y;
            t[6] = (_Float16)xv[nt][kc][1].z; t[7] = (_Float16)xv[nt][kc][1].w;
            bfA[nt][kc] = t;
        }
    __syncthreads();

    // ---- pass A: dense MFMA, all operands LDS/regs
    f32x4 accA[2][9];
    #pragma unroll
    for (int nt = 0; nt < 2; ++nt)
        #pragma unroll
        for (int mt = 0; mt < 9; ++mt) accA[nt][mt] = (f32x4)0.f;
    #pragma unroll
    for (int kc = 0; kc < 4; ++kc) {
        const int k0 = kc * 32 + quad * 8;
        #pragma unroll
        for (int mt = 0; mt < 9; ++mt) {
            const f16x8 af = *(const f16x8*)&Tfl[mt * 16 + col][k0];
            accA[0][mt] = MFMA(af, bfA[0][kc], accA[0][mt], 0, 0, 0);
            accA[1][mt] = MFMA(af, bfA[1][kc], accA[1][mt], 0, 0, 0);
        }
    }
    #pragma unroll
    for (int nt = 0; nt < 2; ++nt) {
        const int ic = (wv * 2 + nt) * 16 + col;
        #pragma unroll
        for (int mt = 0; mt < 9; ++mt)
            #pragma unroll
            for (int r = 0; r < 4; ++r)
                Y1l[mt * 16 + quad * 4 + r][ic] = (_Float16)accA[nt][mt][r];
    }
    __syncthreads();

    // ---- pass B: wave wv covers v-tiles {wv, wv+4, wv+8}; af9 reused across nt
    f32x4 accB[3][9];
    #pragma unroll
    for (int t = 0; t < 3; ++t)
        #pragma unroll
        for (int mt = 0; mt < 9; ++mt) accB[t][mt] = (f32x4)0.f;
    #pragma unroll
    for (int kc = 0; kc < 4; ++kc) {
        const int k0 = kc * 32 + quad * 8;
        f16x8 af9[9];
        #pragma unroll
        for (int mt = 0; mt < 9; ++mt)
            af9[mt] = *(const f16x8*)&Tfl[mt * 16 + col][k0];
        #pragma unroll
        for (int t = 0; t < 3; ++t) {
            const int nt = wv + 4 * t;
            if (nt < 9) {
                const f16x8 bf = *(const f16x8*)&Y1l[nt * 16 + col][k0];
                #pragma unroll
                for (int mt = 0; mt < 9; ++mt)
                    accB[t][mt] = MFMA(af9[mt], bf, accB[t][mt], 0, 0, 0);
            }
        }
    }

    // ---- epilogue: restage acc into Tfl (now dead) as Xl[u][v], vector copy
    __syncthreads();                       // all Tfl/Y1l reads of pass B done
    #pragma unroll
    for (int t = 0; t < 3; ++t) {
        const int nt = wv + 4 * t;
        if (nt < 9) {
            const int vg = nt * 16 + col;
            if (vg < 132) {
                #pragma unroll
                for (int mt = 0; mt < 9; ++mt)
                    #pragma unroll
                    for (int r = 0; r < 4; ++r) {
                        const int u = mt * 16 + quad * 4 + r;
                        if (u < 132) Tfl[u][vg] = (_Float16)accB[t][mt][r];
                    }
            }
        }
    }
    __syncthreads();
    // linear copy-out: 132 rows x 17 f16x8 chunks (cols 132..135 junk, unread)
    _Float16* Xp = X + (size_t)bc * 17952;
    #pragma unroll
    for (int k = 0; k < 9; ++k) {
        const int ch = tid + 256 * k;      // 0..2303, valid < 2244
        if (ch < 2244) {
            const int u = ch / 17, kk = ch - u * 17;
            *(f16x8*)(Xp + u * 136 + kk * 8) = *(const f16x8*)&Tfl[u][kk * 8];
        }
    }
}

// ---------------------------------------------------------- combine MFMA ----
// grid (66 uidx, 8 b), 256 thr (4 waves). Block stages P/M for u1=uidx ONCE
// and emits output rows u1 AND u2=131-uidx (identities: h(u2)=g(u1),
// g(u2)=h(u1), P(u2,v)=P(u1,131-v), M(u2,v)=-M(u1,131-v)).
// bf hoisted per (nt,half): 3 MFMA per ds_read_b128.
__global__ __launch_bounds__(256) void combine_mfma(
    const _Float16* __restrict__ X, const _Float16* __restrict__ hgT,
    const _Float16* __restrict__ cfT, float* __restrict__ out)
{
    const int uidx = blockIdx.x;    // 0..65
    const int b = blockIdx.y;       // 0..7
    const int tid = threadIdx.x;
    const int wv = tid >> 6, lane = tid & 63;
    const int col = lane & 15, quad = lane >> 4;
    const int u2 = 131 - uidx;
    const bool doB = (uidx >= 4);   // u2 <= 127

    __shared__ _Float16 Ps[132][72];   // [v][c], stride 72 (bank-safe)
    __shared__ _Float16 Ms[132][72];

    // ---- stage P/M for all v in 0..131
    {
        const int c = tid >> 2, sub = tid & 3;
        const _Float16* rowd = X + (size_t)(b * 64 + c) * 17952 + (size_t)uidx * 136;
        const _Float16* rowm = X + (size_t)(b * 64 + c) * 17952 + (size_t)u2 * 136;
        #pragma unroll
        for (int k = 0; k < 8; ++k) {
            const int v0 = sub * 32 + 4 * k;
            const f16x4 d = *(const f16x4*)(rowd + v0);
            const f16x4 m = *(const f16x4*)(rowm + (128 - v0));
            #pragma unroll
            for (int i = 0; i < 4; ++i) {
                Ps[v0 + i][c] = d[i] + m[3 - i];   // P(u,v)=X(u,v)+X(131-u,131-v)
                Ms[v0 + i][c] = d[i] - m[3 - i];
            }
        }
        if (sub == 0) {                            // tail v = 128..131
            const f16x4 d = *(const f16x4*)(rowd + 128);
            const f16x4 m = *(const f16x4*)(rowm);
            #pragma unroll
            for (int i = 0; i < 4; ++i) {
                Ps[128 + i][c] = d[i] + m[3 - i];
                Ms[128 + i][c] = d[i] - m[3 - i];
            }
        }
    }
    // ---- per-lane coefficients (indexed by output column v = nt*16+col)
    f16x8 cfv[8];
    #pragma unroll
    for (int nt = 0; nt < 8; ++nt)
        cfv[nt] = *(const f16x8*)(cfT + (size_t)(nt * 16 + col) * 8);

    // ---- hoist h/g fragments for u1 (both outputs use them, swapped)
    const _Float16* hgu = hgT + (size_t)uidx * 6 * 4096;
    const int orow = wv * 16 + col;
    f16x8 hA[3][2], gA[3][2];
    #pragma unroll
    for (int kt = 0; kt < 3; ++kt)
        #pragma unroll
        for (int hf = 0; hf < 2; ++hf) {
            hA[kt][hf] = *(const f16x8*)(hgu + ((size_t)kt * 64 + orow) * 64 + hf * 32 + quad * 8);
            gA[kt][hf] = *(const f16x8*)(hgu + ((size_t)(3 + kt) * 64 + orow) * 64 + hf * 32 + quad * 8);
        }
    __syncthreads();

    float* outA = out + (((size_t)(b * 64 + wv * 16 + quad * 4)) * 128 + uidx) * 128 + col;
    float* outB = out + (((size_t)(b * 64 + wv * 16 + quad * 4)) * 128 + u2) * 128 + col;

    #pragma unroll
    for (int nt = 0; nt < 8; ++nt) {
        const int vA = nt * 16 + col;
        const int vB = 131 - vA;
        const _Float16 csP1 = cfv[nt][1], csP2 = cfv[nt][2];
        const _Float16 csM1 = cfv[nt][4], csM2 = cfv[nt][5];
        {   // output row u1: sum_kt cfP*h(kt)@P + cfM*g(kt)@M
            const f16x8 p0 = *(const f16x8*)&Ps[vA][quad * 8];
            const f16x8 p1 = *(const f16x8*)&Ps[vA][32 + quad * 8];
            const f16x8 m0 = *(const f16x8*)&Ms[vA][quad * 8];
            const f16x8 m1 = *(const f16x8*)&Ms[vA][32 + quad * 8];
            f32x4 aP = (f32x4)0.f, aM = (f32x4)0.f;
            aP = MFMA(hA[0][0], p0, aP, 0, 0, 0);
            aP = MFMA(hA[0][1], p1, aP, 0, 0, 0);
            aM = MFMA(gA[0][0], m0, aM, 0, 0, 0);
            aM = MFMA(gA[0][1], m1, aM, 0, 0, 0);
            aP = MFMA(hA[1][0], scl(p0, csP1), aP, 0, 0, 0);
            aP = MFMA(hA[1][1], scl(p1, csP1), aP, 0, 0, 0);
            aM = MFMA(gA[1][0], scl(m0, csM1), aM, 0, 0, 0);
            aM = MFMA(gA[1][1], scl(m1, csM1), aM, 0, 0, 0);
            aP = MFMA(hA[2][0], scl(p0, csP2), aP, 0, 0, 0);
            aP = MFMA(hA[2][1], scl(p1, csP2), aP, 0, 0, 0);
            aM = MFMA(gA[2][0], scl(m0, csM2), aM, 0, 0, 0);
            aM = MFMA(gA[2][1], scl(m1, csM2), aM, 0, 0, 0);
            #pragma unroll
            for (int r = 0; r < 4; ++r)
                outA[(size_t)r * 16384 + nt * 16] = (aP[r] + aM[r]) * SCALE;
        }
        if (doB) {  // output row u2: sum_kt cfP*g(kt)@Prev - cfM*h(kt)@Mrev
            const f16x8 p0 = *(const f16x8*)&Ps[vB][quad * 8];
            const f16x8 p1 = *(const f16x8*)&Ps[vB][32 + quad * 8];
            const f16x8 m0 = *(const f16x8*)&Ms[vB][quad * 8];
            const f16x8 m1 = *(const f16x8*)&Ms[vB][32 + quad * 8];
            f32x4 bP = (f32x4)0.f, bM = (f32x4)0.f;
            bP = MFMA(gA[0][0], p0, bP, 0, 0, 0);
            bP = MFMA(gA[0][1], p1, bP, 0, 0, 0);
            bM = MFMA(hA[0][0], m0, bM, 0, 0, 0);
            bM = MFMA(hA[0][1], m1, bM, 0, 0, 0);
            bP = MFMA(gA[1][0], scl(p0, csP1), bP, 0, 0, 0);
            bP = MFMA(gA[1][1], scl(p1, csP1), bP, 0, 0, 0);
            bM = MFMA(hA[1][0], scl(m0, csM1), bM, 0, 0, 0);
            bM = MFMA(hA[1][1], scl(m1, csM1), bM, 0, 0, 0);
            bP = MFMA(gA[2][0], scl(p0, csP2), bP, 0, 0, 0);
            bP = MFMA(gA[2][1], scl(p1, csP2), bP, 0, 0, 0);
            bM = MFMA(hA[2][0], scl(m0, csM2), bM, 0, 0, 0);
            bM = MFMA(hA[2][1], scl(m1, csM2), bM, 0, 0, 0);
            #pragma unroll
            for (int r = 0; r < 4; ++r)
                outB[(size_t)r * 16384 + nt * 16] = (bP[r] - bM[r]) * SCALE;
        }
    }
}

// ----------------------------------------------------------------- launch ----
extern "C" void kernel_launch(void* const* d_in, const int* in_sizes, int n_in,
                              void* d_out, int out_size, void* d_ws, size_t ws_size,
                              hipStream_t stream)
{
    const float* x = (const float*)d_in[0];   // fp32 [8,64,128,128]
    const float* w = (const float*)d_in[1];   // fp32 [64,64,3,3]
    char* ws = (char*)d_ws;
    // byte layout:
    //   Tf  f16 @ 0          (36,864 B)      [144][128]
    //   cfT f16 @ 36,864     (2,048 B)       [128][8]
    //   X   f16 @ 65,536     (18,382,848 B)  [512][132][136] (cols 132..135 junk)
    //   hgT f16 @ 18,448,384 (3,244,032 B)   [66][6][64][64]
    // total ~21.7 MB
    _Float16* Tf  = (_Float16*)(ws);
    _Float16* cfT = (_Float16*)(ws + 36864);
    _Float16* X   = (_Float16*)(ws + 65536);
    _Float16* hgT = (_Float16*)(ws + 18448384);

    // one merged builder launch (Tf + cfT + hgT for u<=65)
    build_all<<<dim3(409), dim3(256), 0, stream>>>(w, Tf, cfT, hgT);

    // fused DHT2: x -> X (Tf + Y1 live in LDS, vectorized copy-out)
    dht2_fused<<<dim3(512), dim3(256), 0, stream>>>(x, Tf, X);

    // combine as MFMA GEMM, u-paired: one staging -> rows u and 131-u
    combine_mfma<<<dim3(66, 8), dim3(256), 0, stream>>>(
        X, hgT, cfT, (float*)d_out);
}